// Round 2
// baseline (266.432 us; speedup 1.0000x reference)
//
#include <hip/hip_runtime.h>

typedef unsigned short u16;
typedef unsigned int   u32;
typedef __attribute__((ext_vector_type(8))) short bf8;   // 8 bf16 (4 VGPRs)
typedef __attribute__((ext_vector_type(4))) float f4;    // 4 fp32 (C/D frag)

#define DF __device__ __forceinline__

// ---------- helpers ----------
DF float bf2f(u16 h){ u32 u = ((u32)h) << 16; float f; __builtin_memcpy(&f, &u, 4); return f; }
DF u16 f2bf(float f){ u32 u; __builtin_memcpy(&u, &f, 4); u = (u + 0x7FFFu + ((u >> 16) & 1u)) >> 16; return (u16)u; }
DF float fexp2(float x){ return __builtin_amdgcn_exp2f(x); }
DF float frcp (float x){ return __builtin_amdgcn_rcpf(x); }
DF float tanhF(float x){ float e = fexp2(2.8853900817779268f * x); return 1.0f - 2.0f * frcp(e + 1.0f); }
DF float sigF (float x){ return frcp(1.0f + fexp2(-1.4426950408889634f * x)); }

// packed fragment-ordered weights: [mat 16][ntile 8][kstep 4][lane 64][8 bf16]
DF const bf8* fragp(const u16* packed, int w, int nt, int ks, int lane){
  return reinterpret_cast<const bf8*>(packed + (((w * 32 + nt * 4 + ks) * 64 + lane) * 8));
}

struct WPtrs { const float* p[16]; };

// ---------- K0: pack fp32 weights into MFMA B-fragment order (bf16) ----------
__global__ __launch_bounds__(256) void k_pack(WPtrs wp, u16* __restrict__ packed){
  int bi = blockIdx.x;
  const float* __restrict__ src = wp.p[bi];
  u16* __restrict__ dst = packed + bi * 32 * 64 * 8;
  int lane = threadIdx.x & 63, warp = threadIdx.x >> 6;
  for(int i = warp; i < 32; i += 4){
    int nt = i >> 2, ks = i & 3;
    int col = nt * 16 + (lane & 15);
    int kb  = ks * 32 + (lane >> 4) * 8;
    u16* o = dst + (i * 64 + lane) * 8;
    for(int j = 0; j < 8; j++) o[j] = f2bf(src[(kb + j) * 128 + col]);
  }
}

// ---------- K1: per-node precompute: Ptop, Pbot, res2 ----------
__global__ __launch_bounds__(64) void k_node_pre(
    const float* __restrict__ hidden, const float* __restrict__ inputs,
    const u16* __restrict__ packed,
    const float* __restrict__ res_b1, const float* __restrict__ res_b2,
    float* __restrict__ Ptop, float* __restrict__ Pbot, float* __restrict__ res2)
{
  __shared__ __align__(16) u16 tA[16 * 136];
  __shared__ __align__(16) u16 tB[16 * 136];
  int row0 = blockIdx.x * 16;
  int lane = threadIdx.x;
  for(int c = lane; c < 16 * 128; c += 64){
    int r = c >> 7, cc = c & 127;
    tA[r * 136 + cc] = f2bf(hidden[(row0 + r) * 128 + cc]);
    tB[r * 136 + cc] = f2bf(inputs[(row0 + r) * 128 + cc]);
  }
  __syncthreads();
  int lrow = lane & 15, lk = lane >> 4;
  bf8 a[4];
  for(int k = 0; k < 4; k++) a[k] = *reinterpret_cast<const bf8*>(&tA[lrow * 136 + k * 32 + lk * 8]);
  // Ptop (mat 0), Pbot (mat 1)
  for(int s = 0; s < 2; s++){
    float* __restrict__ out = s ? Pbot : Ptop;
    for(int nt = 0; nt < 8; nt++){
      f4 c = {0.f, 0.f, 0.f, 0.f};
      for(int k = 0; k < 4; k++)
        c = __builtin_amdgcn_mfma_f32_16x16x32_bf16(a[k], *fragp(packed, s, nt, k, lane), c, 0, 0, 0);
      int col = nt * 16 + lrow;
      for(int q = 0; q < 4; q++) out[(row0 + lk * 4 + q) * 128 + col] = c[q];
    }
  }
  // t1 = relu(inputs @ res_w1 + res_b1) -> tA (mat 5)
  {
    bf8 a2[4];
    for(int k = 0; k < 4; k++) a2[k] = *reinterpret_cast<const bf8*>(&tB[lrow * 136 + k * 32 + lk * 8]);
    for(int nt = 0; nt < 8; nt++){
      f4 c = {0.f, 0.f, 0.f, 0.f};
      for(int k = 0; k < 4; k++)
        c = __builtin_amdgcn_mfma_f32_16x16x32_bf16(a2[k], *fragp(packed, 5, nt, k, lane), c, 0, 0, 0);
      int col = nt * 16 + lrow;
      float bb = res_b1[col];
      for(int q = 0; q < 4; q++){
        float v = c[q] + bb; v = v > 0.f ? v : 0.f;
        tA[(lk * 4 + q) * 136 + col] = f2bf(v);
      }
    }
  }
  __syncthreads();
  // res2 = relu(t1 @ res_w2 + res_b2) (mat 6)
  {
    bf8 a3[4];
    for(int k = 0; k < 4; k++) a3[k] = *reinterpret_cast<const bf8*>(&tA[lrow * 136 + k * 32 + lk * 8]);
    for(int nt = 0; nt < 8; nt++){
      f4 c = {0.f, 0.f, 0.f, 0.f};
      for(int k = 0; k < 4; k++)
        c = __builtin_amdgcn_mfma_f32_16x16x32_bf16(a3[k], *fragp(packed, 6, nt, k, lane), c, 0, 0, 0);
      int col = nt * 16 + lrow;
      float bb = res_b2[col];
      for(int q = 0; q < 4; q++){
        float v = c[q] + bb; v = v > 0.f ? v : 0.f;
        res2[(row0 + lk * 4 + q) * 128 + col] = v;
      }
    }
  }
}

// ---------- K2: msg edge MLP second layer + scatter-mean (block = (b, recv)) ----------
__global__ __launch_bounds__(256) void k_msg(
    const float* __restrict__ Ptop, const float* __restrict__ Pbot,
    const float* __restrict__ msg_b1, const float* __restrict__ msg_b2,
    const u16* __restrict__ packed, float* __restrict__ hnode)
{
  __shared__ __align__(16) u16 h1[112 * 136];
  int blk = blockIdx.x;
  int b = blk / 100, r = blk % 100;
  int t = threadIdx.x;
  // phase 1: h1[s'] = tanh(Ptop[r] + Pbot[s] + b1)
  {
    int j = t & 127, half = t >> 7;
    float ptj = Ptop[(b * 100 + r) * 128 + j] + msg_b1[j];
    for(int s1 = half; s1 < 99; s1 += 2){
      int s = s1 + (s1 >= r);
      float pb = Pbot[(b * 100 + s) * 128 + j];
      h1[s1 * 136 + j] = f2bf(tanhF(ptj + pb));
    }
  }
  for(int i = t; i < 13 * 128; i += 256){
    h1[(99 + (i >> 7)) * 136 + (i & 127)] = 0;
  }
  __syncthreads();
  // phase 2: sum_rows tanh(h1 @ msg_w2 + b2) / 99
  int lane = t & 63, w = t >> 6;
  int lrow = lane & 15, lk = lane >> 4;
  bf8 bw[2][4];
  float b2c[2], acc0 = 0.f, acc1 = 0.f;
  for(int j = 0; j < 2; j++){
    int nt = w * 2 + j;
    for(int k = 0; k < 4; k++) bw[j][k] = *fragp(packed, 13, nt, k, lane);
    b2c[j] = msg_b2[nt * 16 + lrow];
  }
  for(int m = 0; m < 7; m++){
    bf8 a[4];
    for(int k = 0; k < 4; k++)
      a[k] = *reinterpret_cast<const bf8*>(&h1[(m * 16 + lrow) * 136 + k * 32 + lk * 8]);
    f4 c0 = {0.f,0.f,0.f,0.f}, c1 = {0.f,0.f,0.f,0.f};
    for(int k = 0; k < 4; k++){
      c0 = __builtin_amdgcn_mfma_f32_16x16x32_bf16(a[k], bw[0][k], c0, 0, 0, 0);
      c1 = __builtin_amdgcn_mfma_f32_16x16x32_bf16(a[k], bw[1][k], c1, 0, 0, 0);
    }
    int rbase = m * 16 + lk * 4;
    for(int q = 0; q < 4; q++){
      if(rbase + q < 99){
        acc0 += tanhF(c0[q] + b2c[0]);
        acc1 += tanhF(c1[q] + b2c[1]);
      }
    }
  }
  acc0 += __shfl_xor(acc0, 16); acc0 += __shfl_xor(acc0, 32);
  acc1 += __shfl_xor(acc1, 16); acc1 += __shfl_xor(acc1, 32);
  if(lane < 16){
    const float inv = 1.0f / 99.0f;
    float* dst = hnode + (b * 100 + r) * 128;
    dst[(w * 2 + 0) * 16 + lane] = acc0 * inv;
    dst[(w * 2 + 1) * 16 + lane] = acc1 * inv;
  }
}

// ---------- K3: present-msg edge MLP + scatter-mean (block = (b, recv)) ----------
__global__ __launch_bounds__(256) void k_pm(
    const float* __restrict__ EA, const float* __restrict__ pm_w1,
    const float* __restrict__ pm_b1, const float* __restrict__ pm_b2,
    const u16* __restrict__ packed, float* __restrict__ pnode)
{
  __shared__ __align__(16) u16 ea[112 * 136];
  __shared__ __align__(16) u16 h1[112 * 136];
  int blk = blockIdx.x;
  int b = blk / 100, r = blk % 100;
  int t = threadIdx.x, lane = t & 63, w = t >> 6;
  // load 99 edge_attr rows (receiver-major gather), fp32 -> bf16
  for(int s1 = w; s1 < 99; s1 += 4){
    int s = s1 + (s1 >= r);
    int e = s * 99 + (r < s ? r : r - 1);
    const float* src = EA + ((size_t)b * 9900 + (size_t)e) * 135;
    ea[s1 * 136 + lane] = f2bf(src[lane]);
    ea[s1 * 136 + 64 + lane] = f2bf(src[64 + lane]);
    if(lane < 7) ea[s1 * 136 + 128 + lane] = f2bf(src[128 + lane]);
    if(lane == 7) ea[s1 * 136 + 135] = 0;
  }
  for(int i = t; i < 13 * 136; i += 256) ea[99 * 136 + i] = 0;
  __syncthreads();
  int lrow = lane & 15, lk = lane >> 4;
  // phase 2: h1 = relu(ea @ pm_w1 + b1)   (K = 128 MFMA + 7-col fp32 VALU tail)
  {
    bf8 bw[2][4]; float b1c[2]; float wt[7][2];
    for(int j = 0; j < 2; j++){
      int nt = w * 2 + j;
      for(int k = 0; k < 4; k++) bw[j][k] = *fragp(packed, 14, nt, k, lane);
      int col = nt * 16 + lrow;
      b1c[j] = pm_b1[col];
      for(int kk = 0; kk < 7; kk++) wt[kk][j] = pm_w1[(128 + kk) * 128 + col];
    }
    for(int m = 0; m < 7; m++){
      bf8 a[4];
      for(int k = 0; k < 4; k++)
        a[k] = *reinterpret_cast<const bf8*>(&ea[(m * 16 + lrow) * 136 + k * 32 + lk * 8]);
      f4 c0 = {0.f,0.f,0.f,0.f}, c1 = {0.f,0.f,0.f,0.f};
      for(int k = 0; k < 4; k++){
        c0 = __builtin_amdgcn_mfma_f32_16x16x32_bf16(a[k], bw[0][k], c0, 0, 0, 0);
        c1 = __builtin_amdgcn_mfma_f32_16x16x32_bf16(a[k], bw[1][k], c1, 0, 0, 0);
      }
      for(int q = 0; q < 4; q++){
        int row = m * 16 + lk * 4 + q;
        bf8 tl = *reinterpret_cast<const bf8*>(&ea[row * 136 + 128]);
        float c0q = c0[q] + b1c[0], c1q = c1[q] + b1c[1];
        for(int kk = 0; kk < 7; kk++){
          float av = bf2f((u16)tl[kk]);
          c0q += av * wt[kk][0];
          c1q += av * wt[kk][1];
        }
        c0q = c0q > 0.f ? c0q : 0.f;
        c1q = c1q > 0.f ? c1q : 0.f;
        h1[row * 136 + (w * 2 + 0) * 16 + lrow] = f2bf(c0q);
        h1[row * 136 + (w * 2 + 1) * 16 + lrow] = f2bf(c1q);
      }
    }
  }
  __syncthreads();
  // phase 3: sum_rows relu(h1 @ pm_w2 + b2) / 99
  {
    bf8 bw[2][4]; float b2c[2], acc0 = 0.f, acc1 = 0.f;
    for(int j = 0; j < 2; j++){
      int nt = w * 2 + j;
      for(int k = 0; k < 4; k++) bw[j][k] = *fragp(packed, 15, nt, k, lane);
      b2c[j] = pm_b2[nt * 16 + lrow];
    }
    for(int m = 0; m < 7; m++){
      bf8 a[4];
      for(int k = 0; k < 4; k++)
        a[k] = *reinterpret_cast<const bf8*>(&h1[(m * 16 + lrow) * 136 + k * 32 + lk * 8]);
      f4 c0 = {0.f,0.f,0.f,0.f}, c1 = {0.f,0.f,0.f,0.f};
      for(int k = 0; k < 4; k++){
        c0 = __builtin_amdgcn_mfma_f32_16x16x32_bf16(a[k], bw[0][k], c0, 0, 0, 0);
        c1 = __builtin_amdgcn_mfma_f32_16x16x32_bf16(a[k], bw[1][k], c1, 0, 0, 0);
      }
      int rbase = m * 16 + lk * 4;
      for(int q = 0; q < 4; q++){
        if(rbase + q < 99){
          float v0 = c0[q] + b2c[0]; acc0 += (v0 > 0.f ? v0 : 0.f);
          float v1 = c1[q] + b2c[1]; acc1 += (v1 > 0.f ? v1 : 0.f);
        }
      }
    }
    acc0 += __shfl_xor(acc0, 16); acc0 += __shfl_xor(acc0, 32);
    acc1 += __shfl_xor(acc1, 16); acc1 += __shfl_xor(acc1, 32);
    if(lane < 16){
      const float inv = 1.0f / 99.0f;
      float* dst = pnode + (b * 100 + r) * 128;
      dst[(w * 2 + 0) * 16 + lane] = acc0 * inv;
      dst[(w * 2 + 1) * 16 + lane] = acc1 * inv;
    }
  }
}

// ---------- K4: GRU gates + out MLP (1 wave per 16 rows) ----------
__global__ __launch_bounds__(64) void k_final(
    const float* __restrict__ hnode, const float* __restrict__ pnode,
    const float* __restrict__ res2, const float* __restrict__ hidden,
    const u16* __restrict__ packed,
    const float* __restrict__ ir_b, const float* __restrict__ ii_b, const float* __restrict__ in_b,
    const float* __restrict__ ob1, const float* __restrict__ ob2, const float* __restrict__ ob3,
    float* __restrict__ out_pred, float* __restrict__ out_hid)
{
  __shared__ __align__(16) u16 tA[16 * 136];  // hidden_node -> hnew -> o2
  __shared__ __align__(16) u16 tB[16 * 136];  // present -> o1
  int row0 = blockIdx.x * 16;
  int lane = threadIdx.x;
  for(int i = lane; i < 16 * 128; i += 64){
    int rr = i >> 7, cc = i & 127;
    tA[rr * 136 + cc] = f2bf(hnode[(row0 + rr) * 128 + cc]);
    tB[rr * 136 + cc] = f2bf(pnode[(row0 + rr) * 128 + cc] + res2[(row0 + rr) * 128 + cc]);
  }
  __syncthreads();
  int lrow = lane & 15, lk = lane >> 4;
  bf8 a[4];
  for(int k = 0; k < 4; k++) a[k] = *reinterpret_cast<const bf8*>(&tA[lrow * 136 + k * 32 + lk * 8]);
  f4 R[8], I[8], Nv[8];
  for(int nt = 0; nt < 8; nt++){
    f4 cr = {0.f,0.f,0.f,0.f}, ci = {0.f,0.f,0.f,0.f}, cn = {0.f,0.f,0.f,0.f};
    for(int k = 0; k < 4; k++){
      cr = __builtin_amdgcn_mfma_f32_16x16x32_bf16(a[k], *fragp(packed, 2, nt, k, lane), cr, 0, 0, 0); // hr
      ci = __builtin_amdgcn_mfma_f32_16x16x32_bf16(a[k], *fragp(packed, 3, nt, k, lane), ci, 0, 0, 0); // hi
      cn = __builtin_amdgcn_mfma_f32_16x16x32_bf16(a[k], *fragp(packed, 4, nt, k, lane), cn, 0, 0, 0); // hh
    }
    R[nt] = cr; I[nt] = ci; Nv[nt] = cn;
  }
  bf8 a2[4];
  for(int k = 0; k < 4; k++) a2[k] = *reinterpret_cast<const bf8*>(&tB[lrow * 136 + k * 32 + lk * 8]);
  for(int nt = 0; nt < 8; nt++){
    int col = nt * 16 + lrow;
    float birv = ir_b[col], biiv = ii_b[col], binv = in_b[col];
    f4 cr = {0.f,0.f,0.f,0.f}, ci = {0.f,0.f,0.f,0.f}, cn = {0.f,0.f,0.f,0.f};
    for(int k = 0; k < 4; k++){
      cr = __builtin_amdgcn_mfma_f32_16x16x32_bf16(a2[k], *fragp(packed, 7, nt, k, lane), cr, 0, 0, 0); // ir
      ci = __builtin_amdgcn_mfma_f32_16x16x32_bf16(a2[k], *fragp(packed, 8, nt, k, lane), ci, 0, 0, 0); // ii
      cn = __builtin_amdgcn_mfma_f32_16x16x32_bf16(a2[k], *fragp(packed, 9, nt, k, lane), cn, 0, 0, 0); // in
    }
    for(int q = 0; q < 4; q++){
      int grow = row0 + lk * 4 + q;
      float rv = sigF(cr[q] + birv + R[nt][q]);
      float iv = sigF(ci[q] + biiv + I[nt][q]);
      float nv = tanhF(cn[q] + binv + rv * Nv[nt][q]);
      float hold = hidden[grow * 128 + col];
      float hnew = (1.f - iv) * nv + iv * hold;
      out_hid[grow * 128 + col] = hnew;
      tA[(lk * 4 + q) * 136 + col] = f2bf(hnew);
    }
  }
  __syncthreads();
  // o1 = relu(hnew @ out_w1 + b1) -> tB
  {
    bf8 a3[4];
    for(int k = 0; k < 4; k++) a3[k] = *reinterpret_cast<const bf8*>(&tA[lrow * 136 + k * 32 + lk * 8]);
    for(int nt = 0; nt < 8; nt++){
      f4 c = {0.f,0.f,0.f,0.f};
      for(int k = 0; k < 4; k++)
        c = __builtin_amdgcn_mfma_f32_16x16x32_bf16(a3[k], *fragp(packed, 10, nt, k, lane), c, 0, 0, 0);
      int col = nt * 16 + lrow;
      float bb = ob1[col];
      for(int q = 0; q < 4; q++){
        float v = c[q] + bb; v = v > 0.f ? v : 0.f;
        tB[(lk * 4 + q) * 136 + col] = f2bf(v);
      }
    }
  }
  __syncthreads();
  // o2 = relu(o1 @ out_w2 + b2) -> tA
  {
    bf8 a4[4];
    for(int k = 0; k < 4; k++) a4[k] = *reinterpret_cast<const bf8*>(&tB[lrow * 136 + k * 32 + lk * 8]);
    for(int nt = 0; nt < 8; nt++){
      f4 c = {0.f,0.f,0.f,0.f};
      for(int k = 0; k < 4; k++)
        c = __builtin_amdgcn_mfma_f32_16x16x32_bf16(a4[k], *fragp(packed, 11, nt, k, lane), c, 0, 0, 0);
      int col = nt * 16 + lrow;
      float bb = ob2[col];
      for(int q = 0; q < 4; q++){
        float v = c[q] + bb; v = v > 0.f ? v : 0.f;
        tA[(lk * 4 + q) * 136 + col] = f2bf(v);
      }
    }
  }
  __syncthreads();
  // pred = o2 @ out_w3 + b3 -> out
  {
    bf8 a5[4];
    for(int k = 0; k < 4; k++) a5[k] = *reinterpret_cast<const bf8*>(&tA[lrow * 136 + k * 32 + lk * 8]);
    for(int nt = 0; nt < 8; nt++){
      f4 c = {0.f,0.f,0.f,0.f};
      for(int k = 0; k < 4; k++)
        c = __builtin_amdgcn_mfma_f32_16x16x32_bf16(a5[k], *fragp(packed, 12, nt, k, lane), c, 0, 0, 0);
      int col = nt * 16 + lrow;
      float bb = ob3[col];
      for(int q = 0; q < 4; q++)
        out_pred[(row0 + lk * 4 + q) * 128 + col] = c[q] + bb;
    }
  }
}

// ---------- host ----------
extern "C" void kernel_launch(void* const* d_in, const int* in_sizes, int n_in,
                              void* d_out, int out_size, void* d_ws, size_t ws_size,
                              hipStream_t stream)
{
  const float* inputs = (const float*)d_in[0];
  const float* edge   = (const float*)d_in[1];
  const float* hidden = (const float*)d_in[2];
  const float* msg_w1 = (const float*)d_in[3];
  const float* msg_b1 = (const float*)d_in[4];
  const float* msg_w2 = (const float*)d_in[5];
  const float* msg_b2 = (const float*)d_in[6];
  const float* pm_w1  = (const float*)d_in[7];
  const float* pm_b1  = (const float*)d_in[8];
  const float* pm_w2  = (const float*)d_in[9];
  const float* pm_b2  = (const float*)d_in[10];
  const float* res_w1 = (const float*)d_in[11];
  const float* res_b1 = (const float*)d_in[12];
  const float* res_w2 = (const float*)d_in[13];
  const float* res_b2 = (const float*)d_in[14];
  const float* ir_w = (const float*)d_in[15]; const float* ir_b = (const float*)d_in[16];
  const float* ii_w = (const float*)d_in[17]; const float* ii_b = (const float*)d_in[18];
  const float* in_w = (const float*)d_in[19]; const float* in_b = (const float*)d_in[20];
  const float* hr_w = (const float*)d_in[21];
  const float* hi_w = (const float*)d_in[22];
  const float* hh_w = (const float*)d_in[23];
  const float* out_w1 = (const float*)d_in[24]; const float* out_b1 = (const float*)d_in[25];
  const float* out_w2 = (const float*)d_in[26]; const float* out_b2 = (const float*)d_in[27];
  const float* out_w3 = (const float*)d_in[28]; const float* out_b3 = (const float*)d_in[29];

  char* ws = (char*)d_ws;
  u16*   packed = (u16*)ws;                                     // 524288 B
  float* Ptop   = (float*)(ws + 524288);                        // 1638400 B each
  float* Pbot   = (float*)(ws + 524288 + 1 * 1638400);
  float* res2   = (float*)(ws + 524288 + 2 * 1638400);
  float* hnode  = (float*)(ws + 524288 + 3 * 1638400);
  float* pnode  = (float*)(ws + 524288 + 4 * 1638400);

  WPtrs wp;
  wp.p[0]  = msg_w1;             // msg_w1 top (recv half)
  wp.p[1]  = msg_w1 + 128 * 128; // msg_w1 bottom (send half)
  wp.p[2]  = hr_w;  wp.p[3]  = hi_w;  wp.p[4]  = hh_w;
  wp.p[5]  = res_w1; wp.p[6] = res_w2;
  wp.p[7]  = ir_w;  wp.p[8]  = ii_w;  wp.p[9]  = in_w;
  wp.p[10] = out_w1; wp.p[11] = out_w2; wp.p[12] = out_w3;
  wp.p[13] = msg_w2; wp.p[14] = pm_w1; wp.p[15] = pm_w2;

  k_pack<<<16, 256, 0, stream>>>(wp, packed);
  k_node_pre<<<200, 64, 0, stream>>>(hidden, inputs, packed, res_b1, res_b2, Ptop, Pbot, res2);
  k_msg<<<3200, 256, 0, stream>>>(Ptop, Pbot, msg_b1, msg_b2, packed, hnode);
  k_pm<<<3200, 256, 0, stream>>>(edge, pm_w1, pm_b1, pm_b2, packed, pnode);
  float* outp = (float*)d_out;
  k_final<<<200, 64, 0, stream>>>(hnode, pnode, res2, hidden, packed,
                                  ir_b, ii_b, in_b, out_b1, out_b2, out_b3,
                                  outp, outp + 32 * 100 * 128);
}